// Round 2
// baseline (361.125 us; speedup 1.0000x reference)
//
#include <hip/hip_runtime.h>
#include <hip/hip_bf16.h>
#include <cmath>

// Problem constants
#define BATCH   4096
#define NUNITS  1024
#define INSIZE  512
#define SIGSZ   6
#define KSIG    (NUNITS * SIGSZ)          // 6144
#define SAVED   (KSIG + NUNITS)           // 7168
#define KTOT    (INSIZE + KSIG + NUNITS)  // 7680
#define OUTW    (NUNITS * (SIGSZ + 1))    // 7168

// Tile config: 128x64 tile, BK=64, 4 waves (each 64x32), grid 512 (2 blocks/CU)
#define BM 128
#define BN 64
#define BK 64
#define NKT (KTOT / BK) // 120

typedef __attribute__((ext_vector_type(8))) short bf16x8;
typedef __attribute__((ext_vector_type(4))) float f32x4;

__device__ __forceinline__ unsigned short f2bf(float f) {
    union { float f; unsigned int u; } c; c.f = f;
    unsigned int u = c.u;
    return (unsigned short)((u + 0x7FFFu + ((u >> 16) & 1u)) >> 16);  // RNE
}

// XOR-swizzled LDS index (ushort units). bytecol in [0,128), row-major 64 bf16/row.
__device__ __forceinline__ int swz(int row, int bytecol) {
    return row * 64 + (((bytecol) ^ ((row & 7) << 4)) >> 1);
}

__global__ __launch_bounds__(256)
void rsig_fused(const float* __restrict__ x,
                const float* __restrict__ sigs,
                const float* __restrict__ states,
                const float* __restrict__ Ww,
                const float* __restrict__ Wb,
                const float* __restrict__ Uw,
                const float* __restrict__ Ub,
                const float* __restrict__ lt,
                float* __restrict__ out)
{
    __shared__ unsigned short lA[2][BM * BK];  // 32 KB
    __shared__ unsigned short lB[2][BN * BK];  // 16 KB

    const int t = threadIdx.x;
    // XCD chunk swizzle: grid 512, 8 XCDs, 64 blocks/XCD chunk (bm-major:
    // each XCD owns 4 A-panels x all 16 bn -> A reuse in per-XCD L2).
    const int p   = blockIdx.x;
    const int lid = (p & 7) * 64 + (p >> 3);
    const int bm  = lid >> 4;   // 0..31
    const int bn  = lid & 15;   // 0..15

    const int lane = t & 63;
    const int w    = t >> 6;    // wave 0..3
    const int wm   = w >> 1;    // 2x2 wave grid; wave tile 64x32
    const int wn   = w & 1;
    const int lr   = lane & 15;
    const int lg   = lane >> 4;

    const int srow = t >> 4;    // staging: 16 rows/pass, 16 float4 cols
    const int sc4  = t & 15;

    f32x4 acc[4][2];
#pragma unroll
    for (int m = 0; m < 4; ++m)
#pragma unroll
        for (int n = 0; n < 2; ++n)
            acc[m][n] = (f32x4)0.f;

    float4 ra[8], rb[4];

    // ---- staging helpers (as lambdas via macros) ----
#define LOAD_REGS(KT)                                                                   \
    {                                                                                   \
        const int kt_ = (KT);                                                           \
        const float* abase; int astr, koff;                                             \
        if (kt_ < 8)        { abase = x;      astr = INSIZE; koff = kt_ * BK; }         \
        else if (kt_ < 104) { abase = sigs;   astr = KSIG;   koff = kt_ * BK - 512; }   \
        else                { abase = states; astr = NUNITS; koff = kt_ * BK - 6656; }  \
        const float* bbase; int bstr, koffb;                                            \
        if (kt_ < 8)        { bbase = Ww; bstr = INSIZE; koffb = kt_ * BK; }            \
        else                { bbase = Uw; bstr = SAVED;  koffb = kt_ * BK - 512; }      \
        _Pragma("unroll")                                                               \
        for (int j = 0; j < 8; ++j)                                                     \
            ra[j] = *(const float4*)(abase + (size_t)(bm * BM + srow + j * 16) * astr + koff + sc4 * 4); \
        _Pragma("unroll")                                                               \
        for (int j = 0; j < 4; ++j)                                                     \
            rb[j] = *(const float4*)(bbase + (size_t)(bn * BN + srow + j * 16) * bstr + koffb + sc4 * 4); \
    }

#define CVT_STORE(BUF)                                                                  \
    {                                                                                   \
        _Pragma("unroll")                                                               \
        for (int j = 0; j < 8; ++j) {                                                   \
            const int rr = srow + j * 16;                                               \
            ushort4 h;                                                                  \
            h.x = f2bf(ra[j].x); h.y = f2bf(ra[j].y);                                   \
            h.z = f2bf(ra[j].z); h.w = f2bf(ra[j].w);                                   \
            *(ushort4*)&lA[BUF][swz(rr, sc4 * 8)] = h;                                  \
        }                                                                               \
        _Pragma("unroll")                                                               \
        for (int j = 0; j < 4; ++j) {                                                   \
            const int rr = srow + j * 16;                                               \
            ushort4 h;                                                                  \
            h.x = f2bf(rb[j].x); h.y = f2bf(rb[j].y);                                   \
            h.z = f2bf(rb[j].z); h.w = f2bf(rb[j].w);                                   \
            *(ushort4*)&lB[BUF][swz(rr, sc4 * 8)] = h;                                  \
        }                                                                               \
    }

    // Prologue: stage tile 0
    LOAD_REGS(0);
    CVT_STORE(0);
    __syncthreads();

    int c = 0;
    for (int kt = 0; kt < NKT; ++kt) {
        if (kt + 1 < NKT) LOAD_REGS(kt + 1);   // in-flight during MFMA below

        // compute from buf c
#pragma unroll
        for (int ks = 0; ks < 2; ++ks) {
            bf16x8 af[4], bfr[2];
#pragma unroll
            for (int m = 0; m < 4; ++m)
                af[m] = *(const bf16x8*)&lA[c][swz(wm * 64 + m * 16 + lr, ks * 64 + lg * 16)];
#pragma unroll
            for (int n = 0; n < 2; ++n)
                bfr[n] = *(const bf16x8*)&lB[c][swz(wn * 32 + n * 16 + lr, ks * 64 + lg * 16)];
#pragma unroll
            for (int m = 0; m < 4; ++m)
#pragma unroll
                for (int n = 0; n < 2; ++n)
                    acc[m][n] = __builtin_amdgcn_mfma_f32_16x16x32_bf16(af[m], bfr[n], acc[m][n], 0, 0, 0);
        }

        if (kt + 1 < NKT) CVT_STORE(c ^ 1);    // other buffer: overlaps nothing hazardous
        __syncthreads();
        c ^= 1;
    }

    // Epilogue: raw = acc + biases; fused sigjoin (level 2) + outputs
    const float tl = expf(lt[0]);
#pragma unroll
    for (int n = 0; n < 2; ++n) {
        const int u = bn * BN + wn * 32 + n * 16 + lr;
        const float bias = Wb[u] + Ub[u];
#pragma unroll
        for (int m = 0; m < 4; ++m) {
            const int rbase = bm * BM + wm * 64 + m * 16 + (lg << 2);
#pragma unroll
            for (int i = 0; i < 4; ++i) {
                const int b = rbase + i;
                const float raw = acc[m][n][i] + bias;
                const float ps  = states[(size_t)b * NUNITS + u];
                const float d   = raw - ps;
                const float* s  = sigs + (size_t)b * KSIG + u * 6;
                const float s0 = s[0], s1 = s[1], s2 = s[2], s3 = s[3], s4 = s[4], s5 = s[5];
                float* o = out + (size_t)b * OUTW + u * 6;
                o[0] = s0 + d;
                o[1] = s1 + tl;
                o[2] = s2 + 0.5f * d * d   + s0 * d;
                o[3] = s3 + 0.5f * d * tl  + s0 * tl;
                o[4] = s4 + 0.5f * tl * d  + s1 * d;
                o[5] = s5 + 0.5f * tl * tl + s1 * tl;
                out[(size_t)b * OUTW + KSIG + u] = raw;
            }
        }
    }
#undef LOAD_REGS
#undef CVT_STORE
}

extern "C" void kernel_launch(void* const* d_in, const int* in_sizes, int n_in,
                              void* d_out, int out_size, void* d_ws, size_t ws_size,
                              hipStream_t stream) {
    const float* x      = (const float*)d_in[0];
    const float* sigs   = (const float*)d_in[1];
    const float* states = (const float*)d_in[2];
    const float* Ww     = (const float*)d_in[3];
    const float* Wb     = (const float*)d_in[4];
    const float* Uw     = (const float*)d_in[5];
    const float* Ub     = (const float*)d_in[6];
    const float* lt     = (const float*)d_in[7];
    float* out = (float*)d_out;

    dim3 grid((BATCH / BM) * (NUNITS / BN));  // 32 * 16 = 512 blocks
    dim3 block(256);
    hipLaunchKernelGGL(rsig_fused, grid, block, 0, stream,
                       x, sigs, states, Ww, Wb, Uw, Ub, lt, out);
}

// Round 3
// 232.871 us; speedup vs baseline: 1.5507x; 1.5507x over previous
//
#include <hip/hip_runtime.h>
#include <hip/hip_bf16.h>
#include <cmath>

// Problem constants
#define BATCH   4096
#define NUNITS  1024
#define INSIZE  512
#define SIGSZ   6
#define KSIG    (NUNITS * SIGSZ)          // 6144
#define SAVED   (KSIG + NUNITS)           // 7168
#define KTOT    (INSIZE + KSIG + NUNITS)  // 7680
#define OUTW    (NUNITS * (SIGSZ + 1))    // 7168

// Tile config: 128x128 tile, BK=64, 1024 threads = 16 waves, each wave 32x32.
// Occupancy is carried INSIDE the block (16 waves co-resident by construction).
#define BM 128
#define BN 128
#define BK 64
#define NKT (KTOT / BK) // 120

typedef __attribute__((ext_vector_type(8))) short bf16x8;
typedef __attribute__((ext_vector_type(4))) float f32x4;

__device__ __forceinline__ unsigned short f2bf(float f) {
    union { float f; unsigned int u; } c; c.f = f;
    unsigned int u = c.u;
    return (unsigned short)((u + 0x7FFFu + ((u >> 16) & 1u)) >> 16);  // RNE
}

// XOR-swizzled LDS index (ushort units). Row-major 64 bf16 (128 B) per row.
__device__ __forceinline__ int swz(int row, int bytecol) {
    return row * 64 + (((bytecol) ^ ((row & 7) << 4)) >> 1);
}

__global__ __launch_bounds__(1024, 4)
void rsig_fused(const float* __restrict__ x,
                const float* __restrict__ sigs,
                const float* __restrict__ states,
                const float* __restrict__ Ww,
                const float* __restrict__ Wb,
                const float* __restrict__ Uw,
                const float* __restrict__ Ub,
                const float* __restrict__ lt,
                float* __restrict__ out)
{
    __shared__ unsigned short lA[2][BM * BK];  // 32 KB
    __shared__ unsigned short lB[2][BN * BK];  // 32 KB

    const int t = threadIdx.x;
    // XCD chunk swizzle: grid 256, 8 XCDs -> 32 blocks/XCD, bm-major chunks:
    // each XCD owns 4 A-panels x all 8 bn -> A panel reuse in its private L2.
    const int p   = blockIdx.x;
    const int lid = (p & 7) * 32 + (p >> 3);
    const int bm  = lid >> 3;   // 0..31
    const int bn  = lid & 7;    // 0..7

    const int lane = t & 63;
    const int w    = t >> 6;    // wave 0..15
    const int wm   = w >> 2;    // 4x4 wave grid; wave tile 32x32
    const int wn   = w & 3;
    const int lr   = lane & 15;
    const int lg   = lane >> 4;

    const int srow = t >> 4;    // staging: 64 rows/pass, 16 float4 cols cover BK=64
    const int sc4  = t & 15;

    f32x4 acc[2][2];
#pragma unroll
    for (int m = 0; m < 2; ++m)
#pragma unroll
        for (int n = 0; n < 2; ++n)
            acc[m][n] = (f32x4)0.f;

    float4 ra[2], rb[2];

#define LOAD_REGS(KT)                                                                   \
    {                                                                                   \
        const int kt_ = (KT);                                                           \
        const float* abase; int astr, koff;                                             \
        if (kt_ < 8)        { abase = x;      astr = INSIZE; koff = kt_ * BK; }         \
        else if (kt_ < 104) { abase = sigs;   astr = KSIG;   koff = kt_ * BK - 512; }   \
        else                { abase = states; astr = NUNITS; koff = kt_ * BK - 6656; }  \
        const float* bbase; int bstr, koffb;                                            \
        if (kt_ < 8)        { bbase = Ww; bstr = INSIZE; koffb = kt_ * BK; }            \
        else                { bbase = Uw; bstr = SAVED;  koffb = kt_ * BK - 512; }      \
        _Pragma("unroll")                                                               \
        for (int j = 0; j < 2; ++j)                                                     \
            ra[j] = *(const float4*)(abase + (size_t)(bm * BM + srow + j * 64) * astr + koff + sc4 * 4); \
        _Pragma("unroll")                                                               \
        for (int j = 0; j < 2; ++j)                                                     \
            rb[j] = *(const float4*)(bbase + (size_t)(bn * BN + srow + j * 64) * bstr + koffb + sc4 * 4); \
    }

#define CVT_STORE(BUF)                                                                  \
    {                                                                                   \
        _Pragma("unroll")                                                               \
        for (int j = 0; j < 2; ++j) {                                                   \
            const int rr = srow + j * 64;                                               \
            ushort4 h;                                                                  \
            h.x = f2bf(ra[j].x); h.y = f2bf(ra[j].y);                                   \
            h.z = f2bf(ra[j].z); h.w = f2bf(ra[j].w);                                   \
            *(ushort4*)&lA[BUF][swz(rr, sc4 * 8)] = h;                                  \
        }                                                                               \
        _Pragma("unroll")                                                               \
        for (int j = 0; j < 2; ++j) {                                                   \
            const int rr = srow + j * 64;                                               \
            ushort4 h;                                                                  \
            h.x = f2bf(rb[j].x); h.y = f2bf(rb[j].y);                                   \
            h.z = f2bf(rb[j].z); h.w = f2bf(rb[j].w);                                   \
            *(ushort4*)&lB[BUF][swz(rr, sc4 * 8)] = h;                                  \
        }                                                                               \
    }

    // Prologue
    LOAD_REGS(0);
    CVT_STORE(0);
    __syncthreads();

    int c = 0;
    for (int kt = 0; kt < NKT; ++kt) {
        if (kt + 1 < NKT) LOAD_REGS(kt + 1);   // in flight across the MFMA section

#pragma unroll
        for (int ks = 0; ks < 2; ++ks) {
            bf16x8 af[2], bfr[2];
#pragma unroll
            for (int m = 0; m < 2; ++m)
                af[m] = *(const bf16x8*)&lA[c][swz(wm * 32 + m * 16 + lr, ks * 64 + lg * 16)];
#pragma unroll
            for (int n = 0; n < 2; ++n)
                bfr[n] = *(const bf16x8*)&lB[c][swz(wn * 32 + n * 16 + lr, ks * 64 + lg * 16)];
#pragma unroll
            for (int m = 0; m < 2; ++m)
#pragma unroll
                for (int n = 0; n < 2; ++n)
                    acc[m][n] = __builtin_amdgcn_mfma_f32_16x16x32_bf16(af[m], bfr[n], acc[m][n], 0, 0, 0);
        }

        if (kt + 1 < NKT) CVT_STORE(c ^ 1);    // waits vmcnt, writes other buffer
        __syncthreads();
        c ^= 1;
    }

    // Epilogue: raw = acc + biases; fused sigjoin (level 2)
    const float tl = expf(lt[0]);
#pragma unroll
    for (int n = 0; n < 2; ++n) {
        const int u = bn * BN + wn * 32 + n * 16 + lr;
        const float bias = Wb[u] + Ub[u];
#pragma unroll
        for (int m = 0; m < 2; ++m) {
            const int rbase = bm * BM + wm * 32 + m * 16 + (lg << 2);
#pragma unroll
            for (int i = 0; i < 4; ++i) {
                const int b = rbase + i;
                const float raw = acc[m][n][i] + bias;
                const float ps  = states[(size_t)b * NUNITS + u];
                const float d   = raw - ps;
                const float* s  = sigs + (size_t)b * KSIG + u * 6;
                const float s0 = s[0], s1 = s[1], s2 = s[2], s3 = s[3], s4 = s[4], s5 = s[5];
                float* o = out + (size_t)b * OUTW + u * 6;
                o[0] = s0 + d;
                o[1] = s1 + tl;
                o[2] = s2 + 0.5f * d * d   + s0 * d;
                o[3] = s3 + 0.5f * d * tl  + s0 * tl;
                o[4] = s4 + 0.5f * tl * d  + s1 * d;
                o[5] = s5 + 0.5f * tl * tl + s1 * tl;
                out[(size_t)b * OUTW + KSIG + u] = raw;
            }
        }
    }
#undef LOAD_REGS
#undef CVT_STORE
}

extern "C" void kernel_launch(void* const* d_in, const int* in_sizes, int n_in,
                              void* d_out, int out_size, void* d_ws, size_t ws_size,
                              hipStream_t stream) {
    const float* x      = (const float*)d_in[0];
    const float* sigs   = (const float*)d_in[1];
    const float* states = (const float*)d_in[2];
    const float* Ww     = (const float*)d_in[3];
    const float* Wb     = (const float*)d_in[4];
    const float* Uw     = (const float*)d_in[5];
    const float* Ub     = (const float*)d_in[6];
    const float* lt     = (const float*)d_in[7];
    float* out = (float*)d_out;

    dim3 grid((BATCH / BM) * (NUNITS / BN));  // 32 * 8 = 256 blocks
    dim3 block(1024);                          // 16 waves, 4/SIMD guaranteed
    hipLaunchKernelGGL(rsig_fused, grid, block, 0, stream,
                       x, sigs, states, Ww, Wb, Uw, Ub, lt, out);
}